// Round 6
// baseline (330.595 us; speedup 1.0000x reference)
//
#include <hip/hip_runtime.h>
#include <hip/hip_bf16.h>

#define NB 8
#define CH 256
#define NN 4096
#define CQK 32
#define LOG2E 1.4426950408889634f

typedef __attribute__((ext_vector_type(4))) float f32x4;
typedef __attribute__((ext_vector_type(8))) short bf16x8;
typedef __attribute__((ext_vector_type(4))) unsigned int u32x4;
typedef unsigned short u16;

// f32 -> bf16 round-to-nearest-even
static __device__ __forceinline__ u16 f2bf(float f) {
  unsigned int u = __float_as_uint(f);
  unsigned int r = (u + 0x7fffu + ((u >> 16) & 1u)) >> 16;
  return (u16)r;
}
static __device__ __forceinline__ float bf2f(u16 h) {
  return __uint_as_float((unsigned int)h << 16);
}

// ---------------------------------------------------------------------------
// Kernel 1: weights -> bf16. Wqk = [Wq*log2e ; Wk] (64 x 256); bqk likewise.
// ---------------------------------------------------------------------------
__global__ void prep_weights(const float* __restrict__ Wq, const float* __restrict__ bq,
                             const float* __restrict__ Wk, const float* __restrict__ bk,
                             const float* __restrict__ Wv,
                             u16* __restrict__ Wqk, u16* __restrict__ Wvb,
                             float* __restrict__ bqk) {
  int i = blockIdx.x * 256 + threadIdx.x;
  if (i < 64 * 256) {
    int o = i >> 8, c = i & 255;
    float w = (o < 32) ? Wq[o * 256 + c] * LOG2E : Wk[(o - 32) * 256 + c];
    Wqk[i] = f2bf(w);
  }
  if (i < 256 * 256) {
    Wvb[i] = f2bf(Wv[i]);
  }
  if (i < 64) bqk[i] = (i < 32) ? bq[i] * LOG2E : bk[i - 32];
}

// ---------------------------------------------------------------------------
// Kernel 2: x [B,C,N] f32 -> xT [B,N,C] bf16  (LDS tile transpose)
// ---------------------------------------------------------------------------
__global__ __launch_bounds__(256) void transpose_x(const float* __restrict__ x,
                                                   u16* __restrict__ xT) {
  __shared__ u16 t[64][66];
  const int n0 = blockIdx.x * 64, c0 = blockIdx.y * 64, b = blockIdx.z;
  const int tid = threadIdx.x;
  const int nl = tid & 63, cl = tid >> 6;
  const float* xp = x + ((size_t)b * CH + c0) * NN + n0;
#pragma unroll
  for (int p = 0; p < 16; ++p) {
    int c = p * 4 + cl;
    t[c][nl] = f2bf(xp[(size_t)c * NN + nl]);
  }
  __syncthreads();
  u16* op = xT + ((size_t)b * NN + n0) * CH + c0;
#pragma unroll
  for (int p = 0; p < 16; ++p) {
    int n = p * 4 + cl;
    op[(size_t)n * CH + nl] = t[nl][n];
  }
}

// ---------------------------------------------------------------------------
// Kernel 3: projection GEMM (bf16 MFMA, K=256, fragments direct from global).
// out[row, col] = sum_k A[row,k]*B[col,k] + bias.
// mode 1 (qk): rows = n. col<32 -> q fragment layout:
//     q[((b*256 + n>>4)*16 + n&15)*32 + col]
//   col>=32 -> k fragment layout with ROW PERMUTATION so QK^T MFMA output
//   lands directly in the PV B-fragment lane layout:
//     position (t = m>>5, ct = (m>>2)&1, p = ((m>>3)&3)*4 + (m&3))
// mode 2 (v): rows = ch, cols = m. v fragment layout:
//     v[((b*128 + m>>5)*256 + ch)*32 + (m&31)]
// ---------------------------------------------------------------------------
__global__ __launch_bounds__(256) void gemm_proj(
    const u16* __restrict__ A, long long a_bs,
    const u16* __restrict__ Bm, long long b_bs,
    const float* __restrict__ bias_r, const float* __restrict__ bias_c,
    u16* __restrict__ out, u16* __restrict__ out2, int mode) {
  const int m0 = blockIdx.x * 64, c0 = blockIdx.y * 64, b = blockIdx.z;
  const int tid = threadIdx.x, w = tid >> 6, l = tid & 63, g = l >> 4, lr = l & 15;
  const f32x4 fzero = {0.f, 0.f, 0.f, 0.f};

  const u16* Ap = A + (size_t)b * a_bs + (size_t)(m0 + w * 16 + lr) * 256 + g * 8;
  const u16* Bp = Bm + (size_t)b * b_bs + (size_t)(c0 + lr) * 256 + g * 8;

  f32x4 acc[4];
#pragma unroll
  for (int ct = 0; ct < 4; ++ct) acc[ct] = fzero;

#pragma unroll
  for (int kk = 0; kk < 8; ++kk) {
    bf16x8 af = *(const bf16x8*)(Ap + kk * 32);
#pragma unroll
    for (int ct = 0; ct < 4; ++ct) {
      bf16x8 bf = *(const bf16x8*)(Bp + (size_t)ct * 16 * 256 + kk * 32);
      acc[ct] = __builtin_amdgcn_mfma_f32_16x16x32_bf16(af, bf, acc[ct], 0, 0, 0);
    }
  }

  if (mode == 1) {
#pragma unroll
    for (int ct = 0; ct < 4; ++ct) {
      int col = ct * 16 + lr;
      float bc = bias_c[col];
#pragma unroll
      for (int r = 0; r < 4; ++r) {
        int row = m0 + w * 16 + g * 4 + r;  // n
        u16 h = f2bf(acc[ct][r] + bc);
        if (col < 32) {
          out[((size_t)(b * 256 + (row >> 4)) * 16 + (row & 15)) * 32 + col] = h;
        } else {
          int m = row, d = col - 32;
          size_t off = (((size_t)(b * 128 + (m >> 5)) * 2 + ((m >> 2) & 1)) * 16 +
                        (((m >> 3) & 3) * 4 + (m & 3))) * 32 + d;
          out2[off] = h;
        }
      }
    }
  } else {
#pragma unroll
    for (int ct = 0; ct < 4; ++ct) {
      int col = c0 + ct * 16 + lr;  // m
#pragma unroll
      for (int r = 0; r < 4; ++r) {
        int row = m0 + w * 16 + g * 4 + r;  // ch
        u16 h = f2bf(acc[ct][r] + bias_r[row]);
        out[((size_t)(b * 128 + (col >> 5)) * 256 + row) * 32 + (col & 31)] = h;
      }
    }
  }
}

// ---------------------------------------------------------------------------
// Kernel 4: warp-autonomous fused attention. NO LDS, NO data barriers.
// Each wave: 16 queries (one n-tile), all 256 channels, full 4096-m sweep in
// 32-m steps. All operands in fragment-native layouts (1KB coalesced loads).
// K rows pre-permuted so S^T = mfma(K,Q) output IS the PV B-fragment: P stays
// in registers. 8 waves/block share each 18KB K/V window via L1, convoyed by
// one bare pacing s_barrier per step. Full-step K/V register ping-pong.
// ---------------------------------------------------------------------------
__global__ __launch_bounds__(512, 2) void attn_fused(
    const u16* __restrict__ qb, const u16* __restrict__ kb8,
    const u16* __restrict__ vb8, const u16* __restrict__ xT,
    const float* __restrict__ gamma_p, float* __restrict__ out) {
  const int bid = blockIdx.x;
  const int b = bid & 7, ntg = bid >> 3;
  const int tid = threadIdx.x, w = tid >> 6, l = tid & 63, g = l >> 4, lr = l & 15;
  const int nt = ntg * 8 + w;
  const int n0 = nt * 16;
  const float gamma0 = gamma_p[0];
  const f32x4 fzero = {0.f, 0.f, 0.f, 0.f};

  bf16x8 qf = *(const bf16x8*)(qb + ((size_t)(b * 256 + nt) * 16 + lr) * 32 + g * 8);

  const u16* kp = kb8 + (size_t)b * 131072 + lr * 32 + g * 8;   // + s*1024 + ct*512
  const u16* vp = vb8 + (size_t)b * 1048576 + lr * 32 + g * 8;  // + s*8192 + cht*512

  f32x4 oacc[16];
#pragma unroll
  for (int i = 0; i < 16; ++i) oacc[i] = fzero;
  float lsum = 0.f;

  // prologue: step 0 into set A
  bf16x8 kfA0 = *(const bf16x8*)(kp);
  bf16x8 kfA1 = *(const bf16x8*)(kp + 512);
  bf16x8 kfB0, kfB1, vfA[16], vfB[16];
#pragma unroll
  for (int c = 0; c < 16; ++c) vfA[c] = *(const bf16x8*)(vp + c * 512);

  for (int it2 = 0; it2 < 64; ++it2) {
    // ============ phase A: step 2*it2, prefetch 2*it2+1 into B ============
    {
      f32x4 s0 = __builtin_amdgcn_mfma_f32_16x16x32_bf16(kfA0, qf, fzero, 0, 0, 0);
      f32x4 s1 = __builtin_amdgcn_mfma_f32_16x16x32_bf16(kfA1, qf, fzero, 0, 0, 0);
      const int sn = 2 * it2 + 1;
      kfB0 = *(const bf16x8*)(kp + (size_t)sn * 1024);
      kfB1 = *(const bf16x8*)(kp + (size_t)sn * 1024 + 512);
#pragma unroll
      for (int c = 0; c < 16; ++c)
        vfB[c] = *(const bf16x8*)(vp + (size_t)sn * 8192 + c * 512);

      float e0 = __builtin_amdgcn_exp2f(s0[0]);
      float e1 = __builtin_amdgcn_exp2f(s0[1]);
      float e2 = __builtin_amdgcn_exp2f(s0[2]);
      float e3 = __builtin_amdgcn_exp2f(s0[3]);
      float e4 = __builtin_amdgcn_exp2f(s1[0]);
      float e5 = __builtin_amdgcn_exp2f(s1[1]);
      float e6 = __builtin_amdgcn_exp2f(s1[2]);
      float e7 = __builtin_amdgcn_exp2f(s1[3]);
      lsum += ((e0 + e1) + (e2 + e3)) + ((e4 + e5) + (e6 + e7));
      u32x4 pw;
      pw[0] = __builtin_amdgcn_perm(__float_as_uint(e1) + 0x8000u, __float_as_uint(e0) + 0x8000u, 0x07060302u);
      pw[1] = __builtin_amdgcn_perm(__float_as_uint(e3) + 0x8000u, __float_as_uint(e2) + 0x8000u, 0x07060302u);
      pw[2] = __builtin_amdgcn_perm(__float_as_uint(e5) + 0x8000u, __float_as_uint(e4) + 0x8000u, 0x07060302u);
      pw[3] = __builtin_amdgcn_perm(__float_as_uint(e7) + 0x8000u, __float_as_uint(e6) + 0x8000u, 0x07060302u);
      bf16x8 pf = __builtin_bit_cast(bf16x8, pw);
#pragma unroll
      for (int c = 0; c < 16; ++c)
        oacc[c] = __builtin_amdgcn_mfma_f32_16x16x32_bf16(vfA[c], pf, oacc[c], 0, 0, 0);
      __builtin_amdgcn_s_barrier();  // pacing only: keep 8 waves L1-convoyed
    }
    // ============ phase B: step 2*it2+1, prefetch next into A ============
    {
      f32x4 s0 = __builtin_amdgcn_mfma_f32_16x16x32_bf16(kfB0, qf, fzero, 0, 0, 0);
      f32x4 s1 = __builtin_amdgcn_mfma_f32_16x16x32_bf16(kfB1, qf, fzero, 0, 0, 0);
      const int sn = (2 * it2 + 2) & 127;
      kfA0 = *(const bf16x8*)(kp + (size_t)sn * 1024);
      kfA1 = *(const bf16x8*)(kp + (size_t)sn * 1024 + 512);
#pragma unroll
      for (int c = 0; c < 16; ++c)
        vfA[c] = *(const bf16x8*)(vp + (size_t)sn * 8192 + c * 512);

      float e0 = __builtin_amdgcn_exp2f(s0[0]);
      float e1 = __builtin_amdgcn_exp2f(s0[1]);
      float e2 = __builtin_amdgcn_exp2f(s0[2]);
      float e3 = __builtin_amdgcn_exp2f(s0[3]);
      float e4 = __builtin_amdgcn_exp2f(s1[0]);
      float e5 = __builtin_amdgcn_exp2f(s1[1]);
      float e6 = __builtin_amdgcn_exp2f(s1[2]);
      float e7 = __builtin_amdgcn_exp2f(s1[3]);
      lsum += ((e0 + e1) + (e2 + e3)) + ((e4 + e5) + (e6 + e7));
      u32x4 pw;
      pw[0] = __builtin_amdgcn_perm(__float_as_uint(e1) + 0x8000u, __float_as_uint(e0) + 0x8000u, 0x07060302u);
      pw[1] = __builtin_amdgcn_perm(__float_as_uint(e3) + 0x8000u, __float_as_uint(e2) + 0x8000u, 0x07060302u);
      pw[2] = __builtin_amdgcn_perm(__float_as_uint(e5) + 0x8000u, __float_as_uint(e4) + 0x8000u, 0x07060302u);
      pw[3] = __builtin_amdgcn_perm(__float_as_uint(e7) + 0x8000u, __float_as_uint(e6) + 0x8000u, 0x07060302u);
      bf16x8 pf = __builtin_bit_cast(bf16x8, pw);
#pragma unroll
      for (int c = 0; c < 16; ++c)
        oacc[c] = __builtin_amdgcn_mfma_f32_16x16x32_bf16(vfB[c], pf, oacc[c], 0, 0, 0);
      __builtin_amdgcn_s_barrier();
    }
  }

  // ---- epilogue: reduce row sums, normalize, gamma*O + x (from xT bf16) ----
  lsum += __shfl_xor(lsum, 16);
  lsum += __shfl_xor(lsum, 32);
  const float linv = 1.f / lsum;

  const u16* xrow = xT + (size_t)(b * NN + n0 + lr) * CH;
  float* ob = out + (size_t)b * CH * NN + n0 + lr;
#pragma unroll
  for (int c = 0; c < 16; ++c) {
    const int chb = c * 16 + g * 4;
    const ushort4 xv = *(const ushort4*)(xrow + chb);
    ob[(size_t)(chb + 0) * NN] = gamma0 * (oacc[c][0] * linv) + bf2f(xv.x);
    ob[(size_t)(chb + 1) * NN] = gamma0 * (oacc[c][1] * linv) + bf2f(xv.y);
    ob[(size_t)(chb + 2) * NN] = gamma0 * (oacc[c][2] * linv) + bf2f(xv.z);
    ob[(size_t)(chb + 3) * NN] = gamma0 * (oacc[c][3] * linv) + bf2f(xv.w);
  }
}

// ---------------------------------------------------------------------------
extern "C" void kernel_launch(void* const* d_in, const int* in_sizes, int n_in,
                              void* d_out, int out_size, void* d_ws, size_t ws_size,
                              hipStream_t stream) {
  const float* x     = (const float*)d_in[0];
  const float* Wq    = (const float*)d_in[1];
  const float* bq    = (const float*)d_in[2];
  const float* Wk    = (const float*)d_in[3];
  const float* bk    = (const float*)d_in[4];
  const float* Wv    = (const float*)d_in[5];
  const float* bv    = (const float*)d_in[6];
  const float* gamma = (const float*)d_in[7];
  float* out = (float*)d_out;

  char* ws = (char*)d_ws;
  u16*   xT   = (u16*)(ws);                 // [B,N,C] bf16        16,777,216 B
  u16*   qbuf = (u16*)(ws + 16777216);      // q fragments          2,097,152 B
  u16*   kbuf = (u16*)(ws + 18874368);      // k fragments (perm)   2,097,152 B
  u16*   vbuf = (u16*)(ws + 20971520);      // v fragments         16,777,216 B
  u16*   Wqk  = (u16*)(ws + 37748736);      // [64,256] bf16           32,768 B
  u16*   Wvb  = (u16*)(ws + 37781504);      // [256,256] bf16         131,072 B
  float* bqk  = (float*)(ws + 37912576);    // [64] f32                   256 B

  prep_weights<<<256, 256, 0, stream>>>(Wq, bq, Wk, bk, Wv, Wqk, Wvb, bqk);
  transpose_x<<<dim3(64, 4, 8), 256, 0, stream>>>(x, xT);
  gemm_proj<<<dim3(64, 1, 8), 256, 0, stream>>>(
      xT, (long long)NN * CH, Wqk, 0,
      nullptr, bqk, qbuf, kbuf, 1);
  gemm_proj<<<dim3(4, 64, 8), 256, 0, stream>>>(
      Wvb, 0, xT, (long long)NN * CH,
      bv, nullptr, vbuf, nullptr, 2);
  attn_fused<<<256, 512, 0, stream>>>(qbuf, kbuf, vbuf, xT, gamma, out);
}

// Round 7
// 248.247 us; speedup vs baseline: 1.3317x; 1.3317x over previous
//
#include <hip/hip_runtime.h>
#include <hip/hip_bf16.h>

#define NB 8
#define CH 256
#define NN 4096
#define CQK 32
#define LOG2E 1.4426950408889634f

typedef __attribute__((ext_vector_type(4))) float f32x4;
typedef __attribute__((ext_vector_type(8))) short bf16x8;
typedef unsigned short u16;

// f32 -> bf16 round-to-nearest-even (no NaN inputs here)
static __device__ __forceinline__ u16 f2bf(float f) {
  unsigned int u = __float_as_uint(f);
  unsigned int r = (u + 0x7fffu + ((u >> 16) & 1u)) >> 16;
  return (u16)r;
}

// ---------------------------------------------------------------------------
// Kernel 1: weights -> bf16. Wqk = [Wq*log2e ; Wk] (64 x 256); bqk likewise.
// ---------------------------------------------------------------------------
__global__ void prep_weights(const float* __restrict__ Wq, const float* __restrict__ bq,
                             const float* __restrict__ Wk, const float* __restrict__ bk,
                             const float* __restrict__ Wv,
                             u16* __restrict__ Wqk, u16* __restrict__ Wvb,
                             float* __restrict__ bqk) {
  int i = blockIdx.x * 256 + threadIdx.x;
  if (i < 64 * 256) {
    int o = i >> 8, c = i & 255;
    float w = (o < 32) ? Wq[o * 256 + c] * LOG2E : Wk[(o - 32) * 256 + c];
    Wqk[i] = f2bf(w);
  }
  if (i < 256 * 256) {
    Wvb[i] = f2bf(Wv[i]);
  }
  if (i < 64) bqk[i] = (i < 32) ? bq[i] * LOG2E : bk[i - 32];
}

// ---------------------------------------------------------------------------
// Kernel 2: x [B,C,N] f32 -> xT [B,N,C] bf16  (LDS tile transpose)
// ---------------------------------------------------------------------------
__global__ __launch_bounds__(256) void transpose_x(const float* __restrict__ x,
                                                   u16* __restrict__ xT) {
  __shared__ u16 t[64][66];
  const int n0 = blockIdx.x * 64, c0 = blockIdx.y * 64, b = blockIdx.z;
  const int tid = threadIdx.x;
  const int nl = tid & 63, cl = tid >> 6;
  const float* xp = x + ((size_t)b * CH + c0) * NN + n0;
#pragma unroll
  for (int p = 0; p < 16; ++p) {
    int c = p * 4 + cl;
    t[c][nl] = f2bf(xp[(size_t)c * NN + nl]);
  }
  __syncthreads();
  u16* op = xT + ((size_t)b * NN + n0) * CH + c0;
#pragma unroll
  for (int p = 0; p < 16; ++p) {
    int n = p * 4 + cl;
    op[(size_t)n * CH + nl] = t[nl][n];
  }
}

// ---------------------------------------------------------------------------
// Kernel 3: projection GEMM (bf16 MFMA, K=256, fragments direct from global).
// out[row, col] = sum_k A[row,k]*B[col,k] + bias.
// ---------------------------------------------------------------------------
__global__ __launch_bounds__(256) void gemm_proj(
    const u16* __restrict__ A, long long a_bs,
    const u16* __restrict__ Bm, long long b_bs,
    const float* __restrict__ bias_r, const float* __restrict__ bias_c,
    int has_br, int has_bc,
    u16* __restrict__ out, long long out_bs, int out_stride) {
  const int m0 = blockIdx.x * 64, c0 = blockIdx.y * 64, b = blockIdx.z;
  const int tid = threadIdx.x, w = tid >> 6, l = tid & 63, g = l >> 4, lr = l & 15;
  const f32x4 fzero = {0.f, 0.f, 0.f, 0.f};

  const u16* Ap = A + (size_t)b * a_bs + (size_t)(m0 + w * 16 + lr) * 256 + g * 8;
  const u16* Bp = Bm + (size_t)b * b_bs + (size_t)(c0 + lr) * 256 + g * 8;

  f32x4 acc[4];
#pragma unroll
  for (int ct = 0; ct < 4; ++ct) acc[ct] = fzero;

#pragma unroll
  for (int kk = 0; kk < 8; ++kk) {
    bf16x8 af = *(const bf16x8*)(Ap + kk * 32);
#pragma unroll
    for (int ct = 0; ct < 4; ++ct) {
      bf16x8 bf = *(const bf16x8*)(Bp + (size_t)ct * 16 * 256 + kk * 32);
      acc[ct] = __builtin_amdgcn_mfma_f32_16x16x32_bf16(af, bf, acc[ct], 0, 0, 0);
    }
  }

#pragma unroll
  for (int ct = 0; ct < 4; ++ct) {
    int col = c0 + ct * 16 + lr;
    float bc = has_bc ? bias_c[col] : 0.f;
#pragma unroll
    for (int r = 0; r < 4; ++r) {
      int row = m0 + w * 16 + g * 4 + r;
      float val = acc[ct][r] + bc + (has_br ? bias_r[row] : 0.f);
      out[(size_t)b * out_bs + (size_t)row * out_stride + col] = f2bf(val);
    }
  }
}

// ---------------------------------------------------------------------------
// Kernel 4: fused attention, 8 waves / 512 threads, SOFTWARE-PIPELINED:
// PV(t) consumes P written at iter t-1; pre-barrier region prepares P(t+1).
// No data dependency crosses the barrier within an iteration.
//   pre-barrier : QK-MFMA(t+1) [kf prefetched last phase], prefetch K(t+2)/
//                 V(t+1), exp2+pack P(t+1) into registers.
//   barrier     : sched_barrier | lgkmcnt(0) | s_barrier | sched_barrier
//                 (global loads stay in flight across it).
//   post-barrier: 8 ds_read of Pb[t&1] (ready since t-1), 2 ds_write of
//                 P(t+1) -> Pb[(t+1)&1], 16 PV MFMA.
// Race-free with 1 barrier/iter: writes to buf b (phase t+1, post-barrier)
// vs reads of buf b (phase t, post-barrier) are separated by barrier(t+1);
// each wave's lgkmcnt(0) retires its own DS ops before arriving.
// ---------------------------------------------------------------------------
#define KLOAD(t, o) (*(const bf16x8*)(kb + (size_t)((((t) & 63) * 64) + wm * 16 + (o)) * 64))
#define VLOAD(t, c, h) (*(const bf16x8*)(vb + (size_t)(c) * 16 * NN + (((t) & 63) * 64) + (h) * 32))

#define EXPPACK(S0, S1, PWA, PWB, MASK) {                                                     \
  float e0 = __builtin_amdgcn_exp2f(S0[0]);                                                   \
  float e1 = __builtin_amdgcn_exp2f(S0[1]);                                                   \
  float e2 = __builtin_amdgcn_exp2f(S0[2]);                                                   \
  float e3 = __builtin_amdgcn_exp2f(S0[3]);                                                   \
  float e4 = __builtin_amdgcn_exp2f(S1[0]);                                                   \
  float e5 = __builtin_amdgcn_exp2f(S1[1]);                                                   \
  float e6 = __builtin_amdgcn_exp2f(S1[2]);                                                   \
  float e7 = __builtin_amdgcn_exp2f(S1[3]);                                                   \
  lsum += (MASK) * (((e0 + e1) + (e2 + e3)) + ((e4 + e5) + (e6 + e7)));                       \
  PWA.x = __builtin_amdgcn_perm(__float_as_uint(e1) + 0x8000u, __float_as_uint(e0) + 0x8000u, 0x07060302u); \
  PWA.y = __builtin_amdgcn_perm(__float_as_uint(e3) + 0x8000u, __float_as_uint(e2) + 0x8000u, 0x07060302u); \
  PWB.x = __builtin_amdgcn_perm(__float_as_uint(e5) + 0x8000u, __float_as_uint(e4) + 0x8000u, 0x07060302u); \
  PWB.y = __builtin_amdgcn_perm(__float_as_uint(e7) + 0x8000u, __float_as_uint(e6) + 0x8000u, 0x07060302u); \
}

#define PBAR() do {                                  \
  __builtin_amdgcn_sched_barrier(0);                 \
  asm volatile("s_waitcnt lgkmcnt(0)");              \
  __builtin_amdgcn_s_barrier();                      \
  __builtin_amdgcn_sched_barrier(0);                 \
} while (0)

// post-barrier block: PV from Pb[BUF] with V regs; write pw -> Pb[BUF^1]
#define PVPHASE(BUF, V0, V1, V2, V3) {                                                        \
  const char* prb = (const char*)Pb + (BUF) * 8192;                                           \
  bf16x8 pa[4], pc[4];                                                                        \
  _Pragma("unroll")                                                                           \
  for (int nt = 0; nt < 4; ++nt) {                                                            \
    const int row = nt * 16 + lr;                                                             \
    const int rswz = (row & 7) << 4;                                                          \
    pa[nt] = *(const bf16x8*)(prb + row * 128 + ((g * 16) ^ rswz));                           \
    pc[nt] = *(const bf16x8*)(prb + row * 128 + ((64 + g * 16) ^ rswz));                      \
  }                                                                                           \
  char* pdst = (char*)Pb + ((BUF) ^ 1) * 8192 + prow * 128;                                   \
  *(uint2*)(pdst + ((wm * 32 + g * 8) ^ wswz)) = pwa;                                         \
  *(uint2*)(pdst + (((wm + 1) * 32 + g * 8) ^ wswz)) = pwb;                                   \
  _Pragma("unroll")                                                                           \
  for (int nt = 0; nt < 4; ++nt) {                                                            \
    oacc[nt][0] = __builtin_amdgcn_mfma_f32_16x16x32_bf16(V0, pa[nt], oacc[nt][0], 0, 0, 0);  \
    oacc[nt][1] = __builtin_amdgcn_mfma_f32_16x16x32_bf16(V1, pa[nt], oacc[nt][1], 0, 0, 0);  \
    oacc[nt][0] = __builtin_amdgcn_mfma_f32_16x16x32_bf16(V2, pc[nt], oacc[nt][0], 0, 0, 0);  \
    oacc[nt][1] = __builtin_amdgcn_mfma_f32_16x16x32_bf16(V3, pc[nt], oacc[nt][1], 0, 0, 0);  \
  }                                                                                           \
}

__global__ __launch_bounds__(512, 4) void attn_fused(
    const u16* __restrict__ qk, const u16* __restrict__ v,
    const float* __restrict__ x, const float* __restrict__ gamma_p,
    float* __restrict__ out) {
  __shared__ __align__(128) char Pb[2][64 * 128];
  __shared__ float lpart[8][16];

  const int b = blockIdx.y;
  const int n0 = blockIdx.x * 64;
  const int tid = threadIdx.x, w = tid >> 6, l = tid & 63, g = l >> 4, lr = l & 15;
  const int wn = w & 3;          // n-tile owned for QK/softmax
  const int wm = (w >> 2) * 2;   // first 16-m subtile owned for QK/softmax
  const float gamma0 = gamma_p[0];
  const f32x4 fzero = {0.f, 0.f, 0.f, 0.f};

  bf16x8 qf = *(const bf16x8*)(qk + ((size_t)b * NN + n0 + wn * 16 + lr) * 64 + g * 8);

  const u16* kb = qk + (size_t)b * NN * 64 + (size_t)lr * 64 + 32 + g * 8;  // + m*64
  const u16* vb = v + ((size_t)b * CH + w * 32 + lr) * (size_t)NN + g * 8;  // + ct*16*NN + m

  f32x4 oacc[4][2];
#pragma unroll
  for (int nt = 0; nt < 4; ++nt)
#pragma unroll
    for (int ct = 0; ct < 2; ++ct) oacc[nt][ct] = fzero;
  float lsum = 0.f;

  const int prow = wn * 16 + lr;
  const int wswz = (prow & 7) << 4;

  // ---- prologue: prepare tile 0 into Pb[0]; prefetch V(0), K(1) ----
  bf16x8 kA0 = KLOAD(0, 0), kA1 = KLOAD(0, 16);
  bf16x8 vA0 = VLOAD(0, 0, 0), vA1 = VLOAD(0, 1, 0), vA2 = VLOAD(0, 0, 1), vA3 = VLOAD(0, 1, 1);
  bf16x8 kB0 = KLOAD(1, 0), kB1 = KLOAD(1, 16);
  bf16x8 vB0, vB1, vB2, vB3;
  uint2 pwa, pwb;
  {
    f32x4 s0 = __builtin_amdgcn_mfma_f32_16x16x32_bf16(kA0, qf, fzero, 0, 0, 0);
    f32x4 s1 = __builtin_amdgcn_mfma_f32_16x16x32_bf16(kA1, qf, fzero, 0, 0, 0);
    EXPPACK(s0, s1, pwa, pwb, 1.0f);
    char* pdst = (char*)Pb + prow * 128;
    *(uint2*)(pdst + ((wm * 32 + g * 8) ^ wswz)) = pwa;
    *(uint2*)(pdst + (((wm + 1) * 32 + g * 8) ^ wswz)) = pwb;
  }

  for (int it2 = 0; it2 < 32; ++it2) {
    // ============ phase even: t = 2*it2; prepare tile t+1 ============
    {
      const int tn = 2 * it2 + 1;
      f32x4 s0 = __builtin_amdgcn_mfma_f32_16x16x32_bf16(kB0, qf, fzero, 0, 0, 0);
      f32x4 s1 = __builtin_amdgcn_mfma_f32_16x16x32_bf16(kB1, qf, fzero, 0, 0, 0);
      kA0 = KLOAD(tn + 1, 0); kA1 = KLOAD(tn + 1, 16);
      vB0 = VLOAD(tn, 0, 0); vB1 = VLOAD(tn, 1, 0); vB2 = VLOAD(tn, 0, 1); vB3 = VLOAD(tn, 1, 1);
      EXPPACK(s0, s1, pwa, pwb, 1.0f);
      PBAR();
      PVPHASE(0, vA0, vA1, vA2, vA3);
    }
    // ============ phase odd: t = 2*it2+1; prepare tile t+1 ============
    {
      const int tn = 2 * it2 + 2;
      const float tmask = (it2 < 31) ? 1.0f : 0.0f;  // exclude wrapped tile 64
      f32x4 s0 = __builtin_amdgcn_mfma_f32_16x16x32_bf16(kA0, qf, fzero, 0, 0, 0);
      f32x4 s1 = __builtin_amdgcn_mfma_f32_16x16x32_bf16(kA1, qf, fzero, 0, 0, 0);
      kB0 = KLOAD(tn + 1, 0); kB1 = KLOAD(tn + 1, 16);
      vA0 = VLOAD(tn, 0, 0); vA1 = VLOAD(tn, 1, 0); vA2 = VLOAD(tn, 0, 1); vA3 = VLOAD(tn, 1, 1);
      EXPPACK(s0, s1, pwa, pwb, tmask);
      PBAR();
      PVPHASE(1, vB0, vB1, vB2, vB3);
    }
  }

  // ---- epilogue: combine row sums across wave pairs, normalize, write ----
  lsum += __shfl_xor(lsum, 16);
  lsum += __shfl_xor(lsum, 32);
  if (l < 16) lpart[w][lr] = lsum;
  __syncthreads();

  const size_t bbase = (size_t)b * CH * NN;
#pragma unroll
  for (int nt = 0; nt < 4; ++nt) {
    const float linv = 1.f / (lpart[nt][lr] + lpart[nt + 4][lr]);
    const int ncol = n0 + nt * 16 + lr;
#pragma unroll
    for (int ct = 0; ct < 2; ++ct) {
      const int cbase = w * 32 + ct * 16 + g * 4;
#pragma unroll
      for (int r = 0; r < 4; ++r) {
        const size_t off = bbase + (size_t)(cbase + r) * NN + ncol;
        out[off] = gamma0 * (oacc[nt][ct][r] * linv) + x[off];
      }
    }
  }
}

// ---------------------------------------------------------------------------
extern "C" void kernel_launch(void* const* d_in, const int* in_sizes, int n_in,
                              void* d_out, int out_size, void* d_ws, size_t ws_size,
                              hipStream_t stream) {
  const float* x     = (const float*)d_in[0];
  const float* Wq    = (const float*)d_in[1];
  const float* bq    = (const float*)d_in[2];
  const float* Wk    = (const float*)d_in[3];
  const float* bk    = (const float*)d_in[4];
  const float* Wv    = (const float*)d_in[5];
  const float* bv    = (const float*)d_in[6];
  const float* gamma = (const float*)d_in[7];
  float* out = (float*)d_out;

  char* ws = (char*)d_ws;
  u16*   xT  = (u16*)(ws);                 // [B,N,C] bf16   16,777,216 B
  u16*   qkb = (u16*)(ws + 16777216);      // [B,N,64] bf16   4,194,304 B
  u16*   vb  = (u16*)(ws + 20971520);      // [B,C,N] bf16   16,777,216 B
  u16*   Wqk = (u16*)(ws + 37748736);      // [64,256] bf16      32,768 B
  u16*   Wvb = (u16*)(ws + 37781504);      // [256,256] bf16    131,072 B
  float* bqk = (float*)(ws + 37912576);    // [64] f32              256 B

  prep_weights<<<256, 256, 0, stream>>>(Wq, bq, Wk, bk, Wv, Wqk, Wvb, bqk);
  transpose_x<<<dim3(64, 4, 8), 256, 0, stream>>>(x, xT);
  gemm_proj<<<dim3(64, 1, 8), 256, 0, stream>>>(
      xT, (long long)NN * CH, Wqk, 0,
      nullptr, bqk, 0, 1,
      qkb, (long long)NN * 64, 64);
  gemm_proj<<<dim3(4, 64, 8), 256, 0, stream>>>(
      Wvb, 0, xT, (long long)NN * CH,
      bv, nullptr, 1, 0,
      vb, (long long)CH * NN, NN);
  attn_fused<<<dim3(64, 8), 512, 0, stream>>>(qkb, vb, x, gamma, out);
}

// Round 8
// 162.273 us; speedup vs baseline: 2.0373x; 1.5298x over previous
//
#include <hip/hip_runtime.h>
#include <hip/hip_bf16.h>

#define NB 8
#define CH 256
#define NN 4096
#define CQK 32
#define LOG2E 1.4426950408889634f

typedef __attribute__((ext_vector_type(4))) float f32x4;
typedef __attribute__((ext_vector_type(8))) short bf16x8;
typedef unsigned short u16;

// f32 -> bf16 round-to-nearest-even (no NaN inputs here)
static __device__ __forceinline__ u16 f2bf(float f) {
  unsigned int u = __float_as_uint(f);
  unsigned int r = (u + 0x7fffu + ((u >> 16) & 1u)) >> 16;
  return (u16)r;
}

// ---------------------------------------------------------------------------
// Kernel 1: weights -> bf16. Wqk = [Wq*log2e ; Wk] (64 x 256); bqk likewise.
// ---------------------------------------------------------------------------
__global__ void prep_weights(const float* __restrict__ Wq, const float* __restrict__ bq,
                             const float* __restrict__ Wk, const float* __restrict__ bk,
                             const float* __restrict__ Wv,
                             u16* __restrict__ Wqk, u16* __restrict__ Wvb,
                             float* __restrict__ bqk) {
  int i = blockIdx.x * 256 + threadIdx.x;
  if (i < 64 * 256) {
    int o = i >> 8, c = i & 255;
    float w = (o < 32) ? Wq[o * 256 + c] * LOG2E : Wk[(o - 32) * 256 + c];
    Wqk[i] = f2bf(w);
  }
  if (i < 256 * 256) {
    Wvb[i] = f2bf(Wv[i]);
  }
  if (i < 64) bqk[i] = (i < 32) ? bq[i] * LOG2E : bk[i - 32];
}

// ---------------------------------------------------------------------------
// Kernel 2: x [B,C,N] f32 -> xT [B,N,C] bf16  (LDS tile transpose)
// ---------------------------------------------------------------------------
__global__ __launch_bounds__(256) void transpose_x(const float* __restrict__ x,
                                                   u16* __restrict__ xT) {
  __shared__ u16 t[64][66];
  const int n0 = blockIdx.x * 64, c0 = blockIdx.y * 64, b = blockIdx.z;
  const int tid = threadIdx.x;
  const int nl = tid & 63, cl = tid >> 6;
  const float* xp = x + ((size_t)b * CH + c0) * NN + n0;
#pragma unroll
  for (int p = 0; p < 16; ++p) {
    int c = p * 4 + cl;
    t[c][nl] = f2bf(xp[(size_t)c * NN + nl]);
  }
  __syncthreads();
  u16* op = xT + ((size_t)b * NN + n0) * CH + c0;
#pragma unroll
  for (int p = 0; p < 16; ++p) {
    int n = p * 4 + cl;
    op[(size_t)n * CH + nl] = t[nl][n];
  }
}

// ---------------------------------------------------------------------------
// Kernel 3: projection GEMM (bf16 MFMA, K=256, fragments direct from global).
// out[row, col] = sum_k A[row,k]*B[col,k] + bias.
// mode 1 (qk): rows = n, cols 0-63. col<32 -> qbuf [B][N][32] packed;
//              col>=32 -> kbuf [B][N][32] packed (k-half only).
// mode 2 (v):  rows = ch, cols = m. fragment-native layout:
//              vbuf[((b*128 + m>>5)*256 + ch)*32 + (m&31)]
// Both make every attention-side global load lane-contiguous (1KB/wave).
// ---------------------------------------------------------------------------
__global__ __launch_bounds__(256) void gemm_proj(
    const u16* __restrict__ A, long long a_bs,
    const u16* __restrict__ Bm, long long b_bs,
    const float* __restrict__ bias_r, const float* __restrict__ bias_c,
    u16* __restrict__ out, u16* __restrict__ out2, int mode) {
  const int m0 = blockIdx.x * 64, c0 = blockIdx.y * 64, b = blockIdx.z;
  const int tid = threadIdx.x, w = tid >> 6, l = tid & 63, g = l >> 4, lr = l & 15;
  const f32x4 fzero = {0.f, 0.f, 0.f, 0.f};

  const u16* Ap = A + (size_t)b * a_bs + (size_t)(m0 + w * 16 + lr) * 256 + g * 8;
  const u16* Bp = Bm + (size_t)b * b_bs + (size_t)(c0 + lr) * 256 + g * 8;

  f32x4 acc[4];
#pragma unroll
  for (int ct = 0; ct < 4; ++ct) acc[ct] = fzero;

#pragma unroll
  for (int kk = 0; kk < 8; ++kk) {
    bf16x8 af = *(const bf16x8*)(Ap + kk * 32);
#pragma unroll
    for (int ct = 0; ct < 4; ++ct) {
      bf16x8 bf = *(const bf16x8*)(Bp + (size_t)ct * 16 * 256 + kk * 32);
      acc[ct] = __builtin_amdgcn_mfma_f32_16x16x32_bf16(af, bf, acc[ct], 0, 0, 0);
    }
  }

  if (mode == 1) {
#pragma unroll
    for (int ct = 0; ct < 4; ++ct) {
      int col = ct * 16 + lr;
      float bc = bias_c[col];
#pragma unroll
      for (int r = 0; r < 4; ++r) {
        int row = m0 + w * 16 + g * 4 + r;  // n
        u16 h = f2bf(acc[ct][r] + bc);
        if (col < 32) {
          out[((size_t)(b * NN + row)) * 32 + col] = h;
        } else {
          out2[((size_t)(b * NN + row)) * 32 + (col - 32)] = h;
        }
      }
    }
  } else {
#pragma unroll
    for (int ct = 0; ct < 4; ++ct) {
      int col = c0 + ct * 16 + lr;  // m
#pragma unroll
      for (int r = 0; r < 4; ++r) {
        int row = m0 + w * 16 + g * 4 + r;  // ch
        u16 h = f2bf(acc[ct][r] + bias_r[row]);
        out[((size_t)(b * 128 + (col >> 5)) * 256 + row) * 32 + (col & 31)] = h;
      }
    }
  }
}

// ---------------------------------------------------------------------------
// Kernel 4: fused attention, 8 waves / 512 threads, software-pipelined as in
// round 7, but ALL global loads are now lane-contiguous 1KB wave loads
// (fragment-native q/k/v layouts) — kills the 16-segment address-gather that
// saturated the CU memory-address pipe at ~193us for four schedules running.
// Grid dim3(8,64): linear_id%8 = batch -> batch pinned to one XCD's L2.
// ---------------------------------------------------------------------------
#define KLOAD(t, o) (*(const bf16x8*)(kp + (size_t)((((t) & 63) * 64) + wm * 16 + (o)) * 32))
#define VLOAD(s, c) (*(const bf16x8*)(vp + (size_t)((s) & 127) * 8192 + (c) * 512))

#define EXPPACK(S0, S1, PWA, PWB, MASK) {                                                     \
  float e0 = __builtin_amdgcn_exp2f(S0[0]);                                                   \
  float e1 = __builtin_amdgcn_exp2f(S0[1]);                                                   \
  float e2 = __builtin_amdgcn_exp2f(S0[2]);                                                   \
  float e3 = __builtin_amdgcn_exp2f(S0[3]);                                                   \
  float e4 = __builtin_amdgcn_exp2f(S1[0]);                                                   \
  float e5 = __builtin_amdgcn_exp2f(S1[1]);                                                   \
  float e6 = __builtin_amdgcn_exp2f(S1[2]);                                                   \
  float e7 = __builtin_amdgcn_exp2f(S1[3]);                                                   \
  lsum += (MASK) * (((e0 + e1) + (e2 + e3)) + ((e4 + e5) + (e6 + e7)));                       \
  PWA.x = __builtin_amdgcn_perm(__float_as_uint(e1) + 0x8000u, __float_as_uint(e0) + 0x8000u, 0x07060302u); \
  PWA.y = __builtin_amdgcn_perm(__float_as_uint(e3) + 0x8000u, __float_as_uint(e2) + 0x8000u, 0x07060302u); \
  PWB.x = __builtin_amdgcn_perm(__float_as_uint(e5) + 0x8000u, __float_as_uint(e4) + 0x8000u, 0x07060302u); \
  PWB.y = __builtin_amdgcn_perm(__float_as_uint(e7) + 0x8000u, __float_as_uint(e6) + 0x8000u, 0x07060302u); \
}

#define PBAR() do {                                  \
  __builtin_amdgcn_sched_barrier(0);                 \
  asm volatile("s_waitcnt lgkmcnt(0)");              \
  __builtin_amdgcn_s_barrier();                      \
  __builtin_amdgcn_sched_barrier(0);                 \
} while (0)

// post-barrier block: PV from Pb[BUF] with V regs; write pw -> Pb[BUF^1]
#define PVPHASE(BUF, V0, V1, V2, V3) {                                                        \
  const char* prb = (const char*)Pb + (BUF) * 8192;                                           \
  bf16x8 pa[4], pc[4];                                                                        \
  _Pragma("unroll")                                                                           \
  for (int nt = 0; nt < 4; ++nt) {                                                            \
    const int row = nt * 16 + lr;                                                             \
    const int rswz = (row & 7) << 4;                                                          \
    pa[nt] = *(const bf16x8*)(prb + row * 128 + ((g * 16) ^ rswz));                           \
    pc[nt] = *(const bf16x8*)(prb + row * 128 + ((64 + g * 16) ^ rswz));                      \
  }                                                                                           \
  char* pdst = (char*)Pb + ((BUF) ^ 1) * 8192 + prow * 128;                                   \
  *(uint2*)(pdst + ((wm * 32 + g * 8) ^ wswz)) = pwa;                                         \
  *(uint2*)(pdst + (((wm + 1) * 32 + g * 8) ^ wswz)) = pwb;                                   \
  _Pragma("unroll")                                                                           \
  for (int nt = 0; nt < 4; ++nt) {                                                            \
    oacc[nt][0] = __builtin_amdgcn_mfma_f32_16x16x32_bf16(V0, pa[nt], oacc[nt][0], 0, 0, 0);  \
    oacc[nt][1] = __builtin_amdgcn_mfma_f32_16x16x32_bf16(V1, pa[nt], oacc[nt][1], 0, 0, 0);  \
    oacc[nt][0] = __builtin_amdgcn_mfma_f32_16x16x32_bf16(V2, pc[nt], oacc[nt][0], 0, 0, 0);  \
    oacc[nt][1] = __builtin_amdgcn_mfma_f32_16x16x32_bf16(V3, pc[nt], oacc[nt][1], 0, 0, 0);  \
  }                                                                                           \
}

__global__ __launch_bounds__(512, 4) void attn_fused(
    const u16* __restrict__ qb, const u16* __restrict__ kbuf,
    const u16* __restrict__ vbuf, const float* __restrict__ x,
    const float* __restrict__ gamma_p, float* __restrict__ out) {
  __shared__ __align__(128) char Pb[2][64 * 128];
  __shared__ float lpart[8][16];

  const int b = blockIdx.x;          // %8 of linear id -> XCD pinning
  const int n0 = blockIdx.y * 64;
  const int tid = threadIdx.x, w = tid >> 6, l = tid & 63, g = l >> 4, lr = l & 15;
  const int wn = w & 3;          // n-tile owned for QK/softmax
  const int wm = (w >> 2) * 2;   // first 16-m subtile owned for QK/softmax
  const float gamma0 = gamma_p[0];
  const f32x4 fzero = {0.f, 0.f, 0.f, 0.f};

  // q fragment (B-operand): contiguous 1KB per wave
  bf16x8 qf = *(const bf16x8*)(qb + ((size_t)b * NN + n0 + wn * 16 + lr) * 32 + g * 8);

  const u16* kp = kbuf + (size_t)b * (NN * 32) + (size_t)lr * 32 + g * 8;
  const u16* vp = vbuf + (size_t)b * 1048576 + (size_t)(w * 32 + lr) * 32 + g * 8;

  f32x4 oacc[4][2];
#pragma unroll
  for (int nt = 0; nt < 4; ++nt)
#pragma unroll
    for (int ct = 0; ct < 2; ++ct) oacc[nt][ct] = fzero;
  float lsum = 0.f;

  const int prow = wn * 16 + lr;
  const int wswz = (prow & 7) << 4;

  // ---- prologue: prepare tile 0 into Pb[0]; prefetch V(0), K(1) ----
  bf16x8 kA0 = KLOAD(0, 0), kA1 = KLOAD(0, 16);
  bf16x8 vA0 = VLOAD(0, 0), vA1 = VLOAD(0, 1), vA2 = VLOAD(1, 0), vA3 = VLOAD(1, 1);
  bf16x8 kB0 = KLOAD(1, 0), kB1 = KLOAD(1, 16);
  bf16x8 vB0, vB1, vB2, vB3;
  uint2 pwa, pwb;
  {
    f32x4 s0 = __builtin_amdgcn_mfma_f32_16x16x32_bf16(kA0, qf, fzero, 0, 0, 0);
    f32x4 s1 = __builtin_amdgcn_mfma_f32_16x16x32_bf16(kA1, qf, fzero, 0, 0, 0);
    EXPPACK(s0, s1, pwa, pwb, 1.0f);
    char* pdst = (char*)Pb + prow * 128;
    *(uint2*)(pdst + ((wm * 32 + g * 8) ^ wswz)) = pwa;
    *(uint2*)(pdst + (((wm + 1) * 32 + g * 8) ^ wswz)) = pwb;
  }

  for (int it2 = 0; it2 < 32; ++it2) {
    // ============ phase even: t = 2*it2; prepare tile t+1 ============
    {
      const int tn = 2 * it2 + 1;
      f32x4 s0 = __builtin_amdgcn_mfma_f32_16x16x32_bf16(kB0, qf, fzero, 0, 0, 0);
      f32x4 s1 = __builtin_amdgcn_mfma_f32_16x16x32_bf16(kB1, qf, fzero, 0, 0, 0);
      kA0 = KLOAD(tn + 1, 0); kA1 = KLOAD(tn + 1, 16);
      vB0 = VLOAD(2 * tn, 0); vB1 = VLOAD(2 * tn, 1);
      vB2 = VLOAD(2 * tn + 1, 0); vB3 = VLOAD(2 * tn + 1, 1);
      EXPPACK(s0, s1, pwa, pwb, 1.0f);
      PBAR();
      PVPHASE(0, vA0, vA1, vA2, vA3);
    }
    // ============ phase odd: t = 2*it2+1; prepare tile t+1 ============
    {
      const int tn = 2 * it2 + 2;
      const float tmask = (it2 < 31) ? 1.0f : 0.0f;  // exclude wrapped tile 64
      f32x4 s0 = __builtin_amdgcn_mfma_f32_16x16x32_bf16(kA0, qf, fzero, 0, 0, 0);
      f32x4 s1 = __builtin_amdgcn_mfma_f32_16x16x32_bf16(kA1, qf, fzero, 0, 0, 0);
      kB0 = KLOAD(tn + 1, 0); kB1 = KLOAD(tn + 1, 16);
      vA0 = VLOAD(2 * tn, 0); vA1 = VLOAD(2 * tn, 1);
      vA2 = VLOAD(2 * tn + 1, 0); vA3 = VLOAD(2 * tn + 1, 1);
      EXPPACK(s0, s1, pwa, pwb, tmask);
      PBAR();
      PVPHASE(1, vB0, vB1, vB2, vB3);
    }
  }

  // ---- epilogue: combine row sums across wave pairs, normalize, write ----
  lsum += __shfl_xor(lsum, 16);
  lsum += __shfl_xor(lsum, 32);
  if (l < 16) lpart[w][lr] = lsum;
  __syncthreads();

  const size_t bbase = (size_t)b * CH * NN;
#pragma unroll
  for (int nt = 0; nt < 4; ++nt) {
    const float linv = 1.f / (lpart[nt][lr] + lpart[nt + 4][lr]);
    const int ncol = n0 + nt * 16 + lr;
#pragma unroll
    for (int ct = 0; ct < 2; ++ct) {
      const int cbase = w * 32 + ct * 16 + g * 4;
#pragma unroll
      for (int r = 0; r < 4; ++r) {
        const size_t off = bbase + (size_t)(cbase + r) * NN + ncol;
        out[off] = gamma0 * (oacc[nt][ct][r] * linv) + x[off];
      }
    }
  }
}

// ---------------------------------------------------------------------------
extern "C" void kernel_launch(void* const* d_in, const int* in_sizes, int n_in,
                              void* d_out, int out_size, void* d_ws, size_t ws_size,
                              hipStream_t stream) {
  const float* x     = (const float*)d_in[0];
  const float* Wq    = (const float*)d_in[1];
  const float* bq    = (const float*)d_in[2];
  const float* Wk    = (const float*)d_in[3];
  const float* bk    = (const float*)d_in[4];
  const float* Wv    = (const float*)d_in[5];
  const float* bv    = (const float*)d_in[6];
  const float* gamma = (const float*)d_in[7];
  float* out = (float*)d_out;

  char* ws = (char*)d_ws;
  u16*   xT   = (u16*)(ws);                 // [B,N,C] bf16        16,777,216 B
  u16*   qbuf = (u16*)(ws + 16777216);      // [B,N,32] packed      2,097,152 B
  u16*   kbuf = (u16*)(ws + 18874368);      // [B,N,32] packed      2,097,152 B
  u16*   vbuf = (u16*)(ws + 20971520);      // v fragments         16,777,216 B
  u16*   Wqk  = (u16*)(ws + 37748736);      // [64,256] bf16           32,768 B
  u16*   Wvb  = (u16*)(ws + 37781504);      // [256,256] bf16         131,072 B
  float* bqk  = (float*)(ws + 37912576);    // [64] f32                   256 B

  prep_weights<<<256, 256, 0, stream>>>(Wq, bq, Wk, bk, Wv, Wqk, Wvb, bqk);
  transpose_x<<<dim3(64, 4, 8), 256, 0, stream>>>(x, xT);
  gemm_proj<<<dim3(64, 1, 8), 256, 0, stream>>>(
      xT, (long long)NN * CH, Wqk, 0,
      nullptr, bqk, qbuf, kbuf, 1);
  gemm_proj<<<dim3(4, 64, 8), 256, 0, stream>>>(
      Wvb, 0, xT, (long long)NN * CH,
      bv, nullptr, vbuf, nullptr, 2);
  attn_fused<<<dim3(8, 64), 512, 0, stream>>>(qbuf, kbuf, vbuf, x, gamma, out);
}